// Round 9
// baseline (191.396 us; speedup 1.0000x reference)
//
#include <hip/hip_runtime.h>

#define LOG2E 1.44269504088896340736f
#define LN2   0.69314718055994530942f
#define S_    8192
#define CHUNK 2048          // steps per block
#define NCH   4             // blocks per sequence
#define TPB   256
#define KPT   8             // 256 threads * 8 steps = 2048
#define NWAVE 4

#if __has_builtin(__builtin_amdgcn_exp2f)
__device__ __forceinline__ float exp2f_(float x){ return __builtin_amdgcn_exp2f(x); }
#else
__device__ __forceinline__ float exp2f_(float x){ return __expf(x * LN2); }
#endif
#if __has_builtin(__builtin_amdgcn_logf)
__device__ __forceinline__ float log2f_(float x){ return __builtin_amdgcn_logf(x); }
#else
__device__ __forceinline__ float log2f_(float x){ return __logf(x) * LOG2E; }
#endif

// async global->LDS, 16B per lane; g is PER-LANE src, l is wave-uniform LDS base
__device__ __forceinline__ void gload16(const void* g, void* l, int ln){
#if __has_builtin(__builtin_amdgcn_global_load_lds)
    __builtin_amdgcn_global_load_lds((const __attribute__((address_space(1))) void*)g,
                                     (__attribute__((address_space(3))) void*)l, 16, 0, 0);
#else
    *(float4*)((char*)l + ln*16) = *(const float4*)g;
#endif
}

// renorm 9-entry nonneg matrix by exact pow2; s += log2 of removed scale
__device__ __forceinline__ void renorm9(float* V, float& s){
    float m = fmaxf(fmaxf(fmaxf(V[0],V[1]),fmaxf(V[2],V[3])),
                    fmaxf(fmaxf(V[4],V[5]),fmaxf(V[6],V[7])));
    m = fmaxf(m, V[8]);
    int e = (__float_as_int(m) >> 23) & 0xff;
    float rs = __int_as_float((254 - e) << 23);   // 2^(127-e), exact
#pragma unroll
    for (int k=0;k<9;++k) V[k] *= rs;
    s += (float)(e - 127);
}

__device__ __forceinline__ void mul33(float* C, const float* A, const float* B){
#pragma unroll
    for (int i=0;i<3;i++){
        float a0=A[i*3], a1=A[i*3+1], a2=A[i*3+2];
#pragma unroll
        for (int j=0;j<3;j++)
            C[i*3+j] = a0*B[j] + a1*B[3+j] + a2*B[6+j];
    }
}

// Block = quarter sequence: blockIdx = 4*b + h, steps [h*2048,(h+1)*2048).
// em: global_load_lds (linear) -> b128 gather; lab: direct coalesced int4.
// Per-thread 8-step semiring fold -> 64-lane shfl tree -> 4-wave serial ->
// 16-float record: V[9], S2, score, e0[3] (e0 valid for h==0).
extern "C" __global__ __launch_bounds__(TPB)
void crf_fwd(const float* __restrict__ em, const int* __restrict__ lab,
             const float* __restrict__ stt, const float* __restrict__ trt,
             const float* __restrict__ ent, float* __restrict__ ws)
{
    const int bid = blockIdx.x;
    const int b = bid >> 2, h = bid & 3;
    const int tid = threadIdx.x, ln = tid & 63, wv = tid >> 6;

    __shared__ float4 emS[CHUNK*3/4];   // 1536 slots = 24 KB, linear global order
    __shared__ float  tT[9];
    __shared__ float  wM[NWAVE][10];
    __shared__ float  wSc[NWAVE];

    const float* emB = em + ((size_t)b*S_ + (size_t)h*CHUNK)*3;
    const int*   lbB = lab + (size_t)b*S_ + h*CHUNK;

    // ---- stage 24KB em -> LDS (6 x 1KB per wave, async, linear) ----
    {
        const char* gb = (const char*)emB;
        char* lb = (char*)&emS[0];
#pragma unroll
        for (int k=0;k<6;++k){
            int c = k*NWAVE + wv;              // chunk 0..23
            gload16(gb + c*1024 + ln*16, lb + c*1024, ln);
        }
    }
    if (tid < 9) tT[tid] = trt[tid];

    // ---- labels: 2 coalesced int4 per thread (steps tid*8..tid*8+7) ----
    const int4* lb4 = (const int4*)lbB;
    int4 lv0 = lb4[2*tid], lv1 = lb4[2*tid+1];

    // linear-domain transition weights (overlaps load latency)
    float W00=__expf(trt[0]), W01=__expf(trt[1]), W02=__expf(trt[2]);
    float W10=__expf(trt[3]), W11=__expf(trt[4]), W12=__expf(trt[5]);
    float W20=__expf(trt[6]), W21=__expf(trt[7]), W22=__expf(trt[8]);

    // prev label: lane l-1's lv1.w == lab[tid*8-1]; lane 0 loads scalar
    const bool head = (h==0 && tid==0);
    int prev_sh = __shfl_up(lv1.w, 1, 64);
    int prev;
    if (ln == 0) prev = head ? 0 : lbB[tid*KPT - 1];  // h>0,tid=0 -> lbB[-1] (same seq)
    else         prev = prev_sh;

    __syncthreads();   // drains vmcnt (global_load_lds) before LDS reads

    // ---- gather own 8 steps: 6 x ds_read_b128, stride 96B ----
    float ew[24];
    {
        const float4* p = &emS[tid*6];
        *(float4*)&ew[0]  = p[0]; *(float4*)&ew[4]  = p[1]; *(float4*)&ew[8]  = p[2];
        *(float4*)&ew[12] = p[3]; *(float4*)&ew[16] = p[4]; *(float4*)&ew[20] = p[5];
    }
    int lw[8] = {lv0.x,lv0.y,lv0.z,lv0.w, lv1.x,lv1.y,lv1.z,lv1.w};

    // ---- fold: V <- V * (W .* E_t), single pow2 scale; score fused ----
    float V[9] = {1,0,0, 0,1,0, 0,0,1};
    float S2 = 0.f, sc = 0.f;
#pragma unroll
    for (int s=0; s<KPT; ++s){
        float ea=ew[3*s], eb=ew[3*s+1], ec=ew[3*s+2];
        int l = lw[s];
        float ee = (l==1) ? eb : ((l==2) ? ec : ea);
        if (head && s==0) sc += stt[l] + ee;     // start transition + e0
        else              sc += tT[prev*3+l] + ee;
        prev = l;
        if (!(head && s==0)) {                    // seq step 0 is alpha0, not a factor
            float E0=__expf(ea), E1=__expf(eb), E2=__expf(ec);
#pragma unroll
            for (int i=0;i<3;i++){
                float a0=V[i*3], a1=V[i*3+1], a2=V[i*3+2];
                V[i*3]  =(a0*W00+a1*W10+a2*W20)*E0;
                V[i*3+1]=(a0*W01+a1*W11+a2*W21)*E1;
                V[i*3+2]=(a0*W02+a1*W12+a2*W22)*E2;
            }
        }
        if (s==3 || s==7) renorm9(V, S2);   // growth <= ~2^40 per 4 steps
    }

    // ---- ordered 64-lane tree: lane i := chunk_i * chunk_{i+off} ----
#pragma unroll
    for (int off=1; off<64; off<<=1){
        float bv[9];
#pragma unroll
        for (int k=0;k<9;++k) bv[k] = __shfl_down(V[k], (unsigned)off, 64);
        float bs2 = __shfl_down(S2, (unsigned)off, 64);
        float C[9]; mul33(C, V, bv);
        S2 += bs2;
        renorm9(C, S2);
#pragma unroll
        for (int k=0;k<9;++k) V[k]=C[k];
    }
#pragma unroll
    for (int off=32; off; off>>=1) sc += __shfl_down(sc, (unsigned)off, 64);

    if (ln==0){
#pragma unroll
        for (int k=0;k<9;++k) wM[wv][k]=V[k];
        wM[wv][9]=S2; wSc[wv]=sc;
    }
    __syncthreads();

    if (tid==0){
        float A[9], As = wM[0][9], scT = wSc[0];
#pragma unroll
        for (int k=0;k<9;++k) A[k]=wM[0][k];
#pragma unroll
        for (int w=1; w<NWAVE; ++w){
            float C[9]; mul33(C, A, wM[w]);
            As += wM[w][9];
            renorm9(C, As);
#pragma unroll
            for (int k=0;k<9;++k) A[k]=C[k];
            scT += wSc[w];
        }
        float* r = ws + (size_t)bid*16;
#pragma unroll
        for (int k=0;k<9;++k) r[k]=A[k];
        r[9]=As; r[10]=scT;
        r[11]=ew[0]; r[12]=ew[1]; r[13]=ew[2];   // e0 (valid when h==0)
    }
}

// chain the 4 quarter-products, fold alpha0 + end transitions, sum NLL
extern "C" __global__ __launch_bounds__(1024)
void crf_fin(const float* __restrict__ ws, const float* __restrict__ stt,
             const float* __restrict__ ent, float* __restrict__ out, int B)
{
    const int b = threadIdx.x;
    float nll = 0.f;
    if (b < B){
        const float* rr = ws + (size_t)b*NCH*16;
        float C[9], S = rr[9], sc = rr[10];
#pragma unroll
        for (int k=0;k<9;++k) C[k]=rr[k];
#pragma unroll
        for (int q=1;q<NCH;++q){
            const float* r = rr + q*16;
            float T[9]; mul33(T, C, r);
#pragma unroll
            for (int k=0;k<9;++k) C[k]=T[k];
            S += r[9]; sc += r[10];
        }
        float a0=(stt[0]+rr[11])*LOG2E, a1=(stt[1]+rr[12])*LOG2E, a2=(stt[2]+rr[13])*LOG2E;
        float am = fmaxf(fmaxf(a0,a1),a2);
        float w0=exp2f_(a0-am), w1=exp2f_(a1-am), w2=exp2f_(a2-am);
        float q0=w0*C[0]+w1*C[3]+w2*C[6];
        float q1=w0*C[1]+w1*C[4]+w2*C[7];
        float q2=w0*C[2]+w1*C[5]+w2*C[8];
        float z = q0*exp2f_(ent[0]*LOG2E) + q1*exp2f_(ent[1]*LOG2E) + q2*exp2f_(ent[2]*LOG2E);
        float logz = (am + S + log2f_(z)) * LN2;
        nll = logz - sc;
    }
#pragma unroll
    for (int off=32; off; off>>=1) nll += __shfl_down(nll, (unsigned)off, 64);
    __shared__ float acc[16];
    if ((threadIdx.x & 63)==0) acc[threadIdx.x>>6] = nll;
    __syncthreads();
    if (threadIdx.x==0){
        float s=0.f;
#pragma unroll
        for (int k=0;k<16;++k) s += acc[k];
        out[0] = s;
    }
}

extern "C" void kernel_launch(void* const* d_in, const int* in_sizes, int n_in,
                              void* d_out, int out_size, void* d_ws, size_t ws_size,
                              hipStream_t stream) {
    const float* em  = (const float*)d_in[0];
    const int*   lab = (const int*)d_in[1];
    const float* stt = (const float*)d_in[2];
    const float* trt = (const float*)d_in[3];
    const float* ent = (const float*)d_in[4];
    float* out = (float*)d_out;
    float* ws  = (float*)d_ws;     // NCH*B*16 floats = 256 KB for B=1024

    const int B = in_sizes[1] / S_;
    crf_fwd<<<NCH*B, TPB, 0, stream>>>(em, lab, stt, trt, ent, ws);
    crf_fin<<<1, 1024, 0, stream>>>(ws, stt, ent, out, B);
}

// Round 10
// 184.762 us; speedup vs baseline: 1.0359x; 1.0359x over previous
//
#include <hip/hip_runtime.h>

#define LOG2E 1.44269504088896340736f
#define LN2   0.69314718055994530942f
#define S_    8192
#define WCH   512           // steps per (single-wave) block
#define NCH   16            // chunks per sequence
#define KPT   8             // steps per lane

#if __has_builtin(__builtin_amdgcn_exp2f)
__device__ __forceinline__ float exp2f_(float x){ return __builtin_amdgcn_exp2f(x); }
#else
__device__ __forceinline__ float exp2f_(float x){ return __expf(x * LN2); }
#endif
#if __has_builtin(__builtin_amdgcn_logf)
__device__ __forceinline__ float log2f_(float x){ return __builtin_amdgcn_logf(x); }
#else
__device__ __forceinline__ float log2f_(float x){ return __logf(x) * LOG2E; }
#endif

// renorm 9-entry nonneg matrix by exact pow2; s += log2 of removed scale
__device__ __forceinline__ void renorm9(float* V, float& s){
    float m = fmaxf(fmaxf(fmaxf(V[0],V[1]),fmaxf(V[2],V[3])),
                    fmaxf(fmaxf(V[4],V[5]),fmaxf(V[6],V[7])));
    m = fmaxf(m, V[8]);
    int e = (__float_as_int(m) >> 23) & 0xff;
    float rs = __int_as_float((254 - e) << 23);   // 2^(127-e), exact
#pragma unroll
    for (int k=0;k<9;++k) V[k] *= rs;
    s += (float)(e - 127);
}

__device__ __forceinline__ void mul33(float* C, const float* A, const float* B){
#pragma unroll
    for (int i=0;i<3;i++){
        float a0=A[i*3], a1=A[i*3+1], a2=A[i*3+2];
#pragma unroll
        for (int j=0;j<3;j++)
            C[i*3+j] = a0*B[j] + a1*B[3+j] + a2*B[6+j];
    }
}

// One wave per block. blockIdx = b*16 + h -> steps [h*512, (h+1)*512).
// Lane l folds steps h*512 + l*8 .. +7. No barriers, no staging, no
// cross-wave phase. Record (16 floats): V[9], S2, score, e0[3].
extern "C" __global__ __launch_bounds__(64)
void crf_fwd(const float* __restrict__ em, const int* __restrict__ lab,
             const float* __restrict__ stt, const float* __restrict__ trt,
             const float* __restrict__ ent, float* __restrict__ ws)
{
    const int bid = blockIdx.x;
    const int b = bid >> 4, h = bid & 15;
    const int ln = threadIdx.x;             // 0..63

    __shared__ float tT[9];

    const float* emB = em + ((size_t)b*S_ + (size_t)h*WCH)*3;
    const int*   lbB = lab + (size_t)b*S_ + h*WCH;

    // ---- emissions: 6 float4 per lane, 96B/lane footprint (lines fully consumed) ----
    const float4* ep = (const float4*)emB + ln*6;
    float4 r0=ep[0], r1=ep[1], r2=ep[2], r3=ep[3], r4=ep[4], r5=ep[5];

    // ---- labels: 2 coalesced int4 per lane ----
    const int4* lb4 = (const int4*)lbB;
    int4 lv0 = lb4[2*ln], lv1 = lb4[2*ln+1];

    if (ln < 9) tT[ln] = trt[ln];

    // wave-uniform linear-domain transition weights (scalar path)
    float W00=__expf(trt[0]), W01=__expf(trt[1]), W02=__expf(trt[2]);
    float W10=__expf(trt[3]), W11=__expf(trt[4]), W12=__expf(trt[5]);
    float W20=__expf(trt[6]), W21=__expf(trt[7]), W22=__expf(trt[8]);

    // prev label seam: lane l-1's last label == lab[t0-1]; lane 0 scalar load
    const bool head = (h==0 && ln==0);
    int prev_sh = __shfl_up(lv1.w, 1, 64);
    int prev;
    if (ln == 0) prev = head ? 0 : lbB[-1];   // h>0: previous chunk, same sequence
    else         prev = prev_sh;

    __syncthreads();   // single-wave: just a waitcnt for tT

    float ew[24];
    *(float4*)&ew[0]=r0;  *(float4*)&ew[4]=r1;  *(float4*)&ew[8]=r2;
    *(float4*)&ew[12]=r3; *(float4*)&ew[16]=r4; *(float4*)&ew[20]=r5;
    int lw[8] = {lv0.x,lv0.y,lv0.z,lv0.w, lv1.x,lv1.y,lv1.z,lv1.w};

    // ---- fold: V <- V * (W .* E_t), single pow2 scale; score fused ----
    float V[9] = {1,0,0, 0,1,0, 0,0,1};
    float S2 = 0.f, sc = 0.f;
#pragma unroll
    for (int s=0; s<KPT; ++s){
        float ea=ew[3*s], eb=ew[3*s+1], ec=ew[3*s+2];
        int l = lw[s];
        float ee = (l==1) ? eb : ((l==2) ? ec : ea);
        if (head && s==0) sc += stt[l] + ee;      // start transition + e0
        else              sc += tT[prev*3+l] + ee;
        prev = l;
        if (!(head && s==0)) {                     // seq step 0 is alpha0, not a factor
            float E0=__expf(ea), E1=__expf(eb), E2=__expf(ec);
#pragma unroll
            for (int i=0;i<3;i++){
                float a0=V[i*3], a1=V[i*3+1], a2=V[i*3+2];
                V[i*3]  =(a0*W00+a1*W10+a2*W20)*E0;
                V[i*3+1]=(a0*W01+a1*W11+a2*W21)*E1;
                V[i*3+2]=(a0*W02+a1*W12+a2*W22)*E2;
            }
        }
        if (s==3 || s==7) renorm9(V, S2);   // growth <= ~2^40 per 4 steps
    }

    // ---- ordered 64-lane tree: lane i := chunk_i * chunk_{i+off} ----
#pragma unroll
    for (int off=1; off<64; off<<=1){
        float bv[9];
#pragma unroll
        for (int k=0;k<9;++k) bv[k] = __shfl_down(V[k], (unsigned)off, 64);
        float bs2 = __shfl_down(S2, (unsigned)off, 64);
        float C[9]; mul33(C, V, bv);
        S2 += bs2;
        renorm9(C, S2);
#pragma unroll
        for (int k=0;k<9;++k) V[k]=C[k];
    }
#pragma unroll
    for (int off=32; off; off>>=1) sc += __shfl_down(sc, (unsigned)off, 64);

    if (ln == 0){
        float* r = ws + (size_t)bid*16;
#pragma unroll
        for (int k=0;k<9;++k) r[k]=V[k];
        r[9]=S2; r[10]=sc;
        r[11]=ew[0]; r[12]=ew[1]; r[13]=ew[2];   // e0 (valid when h==0)
    }
}

// stage 1: one thread per sequence, chain 16 records -> per-block partial sum
extern "C" __global__ __launch_bounds__(64)
void crf_fin1(const float* __restrict__ ws, const float* __restrict__ stt,
              const float* __restrict__ ent, float* __restrict__ partial)
{
    const int q = blockIdx.x*64 + threadIdx.x;   // sequence id 0..1023
    const float* rr = ws + (size_t)q*NCH*16;
    float C[9], S = rr[9], sc = rr[10];
#pragma unroll
    for (int k=0;k<9;++k) C[k]=rr[k];
#pragma unroll
    for (int p=1;p<NCH;++p){
        const float* r = rr + p*16;
        float T[9]; mul33(T, C, r);
        S += r[9]; sc += r[10];
        renorm9(T, S);
#pragma unroll
        for (int k=0;k<9;++k) C[k]=T[k];
    }
    float a0=(stt[0]+rr[11])*LOG2E, a1=(stt[1]+rr[12])*LOG2E, a2=(stt[2]+rr[13])*LOG2E;
    float am = fmaxf(fmaxf(a0,a1),a2);
    float w0=exp2f_(a0-am), w1=exp2f_(a1-am), w2=exp2f_(a2-am);
    float q0=w0*C[0]+w1*C[3]+w2*C[6];
    float q1=w0*C[1]+w1*C[4]+w2*C[7];
    float q2=w0*C[2]+w1*C[5]+w2*C[8];
    float z = q0*exp2f_(ent[0]*LOG2E) + q1*exp2f_(ent[1]*LOG2E) + q2*exp2f_(ent[2]*LOG2E);
    float logz = (am + S + log2f_(z)) * LN2;
    float nll = logz - sc;
#pragma unroll
    for (int off=32; off; off>>=1) nll += __shfl_down(nll, (unsigned)off, 64);
    if (threadIdx.x==0) partial[blockIdx.x] = nll;
}

// stage 2: sum the 16 partials
extern "C" __global__ __launch_bounds__(64)
void crf_fin2(const float* __restrict__ partial, float* __restrict__ out)
{
    float v = (threadIdx.x < 16) ? partial[threadIdx.x] : 0.f;
#pragma unroll
    for (int off=32; off; off>>=1) v += __shfl_down(v, (unsigned)off, 64);
    if (threadIdx.x==0) out[0] = v;
}

extern "C" void kernel_launch(void* const* d_in, const int* in_sizes, int n_in,
                              void* d_out, int out_size, void* d_ws, size_t ws_size,
                              hipStream_t stream) {
    const float* em  = (const float*)d_in[0];
    const int*   lab = (const int*)d_in[1];
    const float* stt = (const float*)d_in[2];
    const float* trt = (const float*)d_in[3];
    const float* ent = (const float*)d_in[4];
    float* out = (float*)d_out;
    float* ws  = (float*)d_ws;                 // records: NCH*B*16 floats = 1 MB
    const int B = in_sizes[1] / S_;            // 1024
    float* partial = ws + (size_t)NCH*B*16;    // +16 floats

    crf_fwd<<<NCH*B, 64, 0, stream>>>(em, lab, stt, trt, ent, ws);
    crf_fin1<<<B/64, 64, 0, stream>>>(ws, stt, ent, partial);
    crf_fin2<<<1, 64, 0, stream>>>(partial, out);
}

// Round 11
// 184.569 us; speedup vs baseline: 1.0370x; 1.0010x over previous
//
#include <hip/hip_runtime.h>

typedef float f32x2 __attribute__((ext_vector_type(2)));

#define LOG2E 1.44269504088896340736f
#define LN2   0.69314718055994530942f
#define S_    8192
#define WSTEP 1024          // steps per wave
#define NCH   8             // waves per sequence
#define NWAVE 4             // waves per block (independent, no barriers)

#if __has_builtin(__builtin_amdgcn_exp2f)
__device__ __forceinline__ float exp2f_(float x){ return __builtin_amdgcn_exp2f(x); }
#else
__device__ __forceinline__ float exp2f_(float x){ return __expf(x * LN2); }
#endif
#if __has_builtin(__builtin_amdgcn_logf)
__device__ __forceinline__ float log2f_(float x){ return __builtin_amdgcn_logf(x); }
#else
__device__ __forceinline__ float log2f_(float x){ return __logf(x) * LOG2E; }
#endif

// ---- packed 3x3 column state: L[j] = (V[0][j],V[1][j]), H[j] = V[2][j] ----
#define RNORM(L0,L1,L2,H0,H1,H2,S2) { \
    f32x2 _m2 = __builtin_elementwise_max(__builtin_elementwise_max(L0,L1),L2); \
    float _m  = fmaxf(fmaxf(_m2.x,_m2.y), fmaxf(fmaxf(H0,H1),H2)); \
    int _e = (__float_as_int(_m) >> 23) & 0xff; \
    float _rs = __int_as_float((254 - _e) << 23); \
    L0*=_rs; L1*=_rs; L2*=_rs; H0*=_rs; H1*=_rs; H2*=_rs; \
    S2 += (float)(_e - 127); }

// one semiring step: V <- (V @ W) .* colE
#define STEPM(L0,L1,L2,H0,H1,H2, ea,eb,ec) { \
    float _E0=__expf(ea), _E1=__expf(eb), _E2=__expf(ec); \
    f32x2 _n0=(L0*W00+L1*W10+L2*W20)*_E0; float _q0=(H0*W00+H1*W10+H2*W20)*_E0; \
    f32x2 _n1=(L0*W01+L1*W11+L2*W21)*_E1; float _q1=(H0*W01+H1*W11+H2*W21)*_E1; \
    f32x2 _n2=(L0*W02+L1*W12+L2*W22)*_E2; float _q2=(H0*W02+H1*W12+H2*W22)*_E2; \
    L0=_n0; L1=_n1; L2=_n2; H0=_q0; H1=_q1; H2=_q2; }

// C = A @ B (A earlier, B later), packed-column form
#define COMBINE(AL0,AL1,AL2,AH0,AH1,AH2, BL0,BL1,BL2,BH0,BH1,BH2) { \
    f32x2 _c0 = AL0*BL0.x + AL1*BL0.y + AL2*BH0; \
    float _d0 = AH0*BL0.x + AH1*BL0.y + AH2*BH0; \
    f32x2 _c1 = AL0*BL1.x + AL1*BL1.y + AL2*BH1; \
    float _d1 = AH0*BL1.x + AH1*BL1.y + AH2*BH1; \
    f32x2 _c2 = AL0*BL2.x + AL1*BL2.y + AL2*BH2; \
    float _d2 = AH0*BL2.x + AH1*BL2.y + AH2*BH2; \
    AL0=_c0; AL1=_c1; AL2=_c2; AH0=_d0; AH1=_d1; AH2=_d2; }

__device__ __forceinline__ void mul33(float* C, const float* A, const float* B){
#pragma unroll
    for (int i=0;i<3;i++){
        float a0=A[i*3], a1=A[i*3+1], a2=A[i*3+2];
#pragma unroll
        for (int j=0;j<3;j++)
            C[i*3+j] = a0*B[j] + a1*B[3+j] + a2*B[6+j];
    }
}
__device__ __forceinline__ void renorm9(float* V, float& s){
    float m = fmaxf(fmaxf(fmaxf(V[0],V[1]),fmaxf(V[2],V[3])),
                    fmaxf(fmaxf(V[4],V[5]),fmaxf(V[6],V[7])));
    m = fmaxf(m, V[8]);
    int e = (__float_as_int(m) >> 23) & 0xff;
    float rs = __int_as_float((254 - e) << 23);
#pragma unroll
    for (int k=0;k<9;++k) V[k] *= rs;
    s += (float)(e - 127);
}

// Wave g = blockIdx*4+wv owns steps [h*1024,(h+1)*1024) of sequence b (g=b*8+h).
// Lane l folds two adjacent 8-step chains (steps 16l..16l+7 and 16l+8..16l+15),
// combines in-register, then one ordered 64-lane shfl tree. No barriers.
// Record (16 floats @ ws[g*16]): V row-major[9], S2, score, e0[3], pad[2].
extern "C" __global__ __launch_bounds__(256)
void crf_fwd(const float* __restrict__ em, const int* __restrict__ lab,
             const float* __restrict__ stt, const float* __restrict__ trt,
             const float* __restrict__ ent, float* __restrict__ ws)
{
    const int wv = threadIdx.x >> 6, ln = threadIdx.x & 63;
    const int g = blockIdx.x*NWAVE + wv;
    const int b = g >> 3, h = g & 7;

    __shared__ float tTw[NWAVE][12];     // per-wave copy: no cross-wave sync needed
    if (ln < 9) tTw[wv][ln] = trt[ln];

    const float* emB = em + ((size_t)b*S_ + (size_t)h*WSTEP)*3;
    const int*   lbB = lab + (size_t)b*S_ + h*WSTEP;

    // ---- emissions: 12 float4/lane (steps 16l..16l+15), 192B/lane span ----
    float ew[48];
    {
        const float4* ep = (const float4*)emB + ln*12;
#pragma unroll
        for (int k=0;k<12;++k){
            float4 v = ep[k];
            ew[4*k]=v.x; ew[4*k+1]=v.y; ew[4*k+2]=v.z; ew[4*k+3]=v.w;
        }
    }
    // ---- labels: 4 int4/lane, packed 2 bits each into pa (steps 0-7), pb (8-15) ----
    int pa, pb, lastl;
    {
        const int4* lp = (const int4*)lbB + ln*4;
        int4 a = lp[0], c = lp[1], d = lp[2], e = lp[3];
        pa = a.x | (a.y<<2) | (a.z<<4) | (a.w<<6) | (c.x<<8) | (c.y<<10) | (c.z<<12) | (c.w<<14);
        pb = d.x | (d.y<<2) | (d.z<<4) | (d.w<<6) | (e.x<<8) | (e.y<<10) | (e.z<<12) | (e.w<<14);
        lastl = e.w;
    }

    // wave-uniform linear-domain transition weights
    float W00=__expf(trt[0]), W01=__expf(trt[1]), W02=__expf(trt[2]);
    float W10=__expf(trt[3]), W11=__expf(trt[4]), W12=__expf(trt[5]);
    float W20=__expf(trt[6]), W21=__expf(trt[7]), W22=__expf(trt[8]);
    float st0=stt[0], st1=stt[1], st2=stt[2];

    // prev-label seam: lane l-1's step-15 label; lane 0 reads lbB[-1] (h>0)
    int prevA = __shfl_up(lastl, 1, 64);
    if (ln == 0) prevA = (h == 0) ? 0 : lbB[-1];
    int prevB = (pa >> 14) & 3;        // label of step 7
    const bool head = (h==0 && ln==0);

    // ---- two independent 8-step chains, interleaved for ILP ----
    f32x2 AL0={1,0}, AL1={0,1}, AL2={0,0};  float AH0=0, AH1=0, AH2=1;
    f32x2 BL0={1,0}, BL1={0,1}, BL2={0,0};  float BH0=0, BH1=0, BH2=1;
    float S2 = 0.f, sc = 0.f;

#pragma unroll
    for (int s=0; s<8; ++s){
        // chain A: step s
        {
            float ea=ew[3*s], eb=ew[3*s+1], ec=ew[3*s+2];
            int l = (pa >> (2*s)) & 3;
            float ee = (l==1) ? eb : ((l==2) ? ec : ea);
            if (head && s==0){
                float sv = (l==1) ? st1 : ((l==2) ? st2 : st0);
                sc += sv + ee;
            } else {
                sc += tTw[wv][prevA*3+l] + ee;
            }
            prevA = l;
            if (!(head && s==0)) STEPM(AL0,AL1,AL2,AH0,AH1,AH2, ea,eb,ec);
        }
        // chain B: step s+8
        {
            float ea=ew[24+3*s], eb=ew[24+3*s+1], ec=ew[24+3*s+2];
            int l = (pb >> (2*s)) & 3;
            float ee = (l==1) ? eb : ((l==2) ? ec : ea);
            sc += tTw[wv][prevB*3+l] + ee;
            prevB = l;
            STEPM(BL0,BL1,BL2,BH0,BH1,BH2, ea,eb,ec);
        }
        if (s==3 || s==7){               // growth <= ~2^45 per 4 steps
            RNORM(AL0,AL1,AL2,AH0,AH1,AH2, S2);
            RNORM(BL0,BL1,BL2,BH0,BH1,BH2, S2);
        }
    }

    // ---- combine: V = A @ B (16 adjacent steps), then 64-lane ordered tree ----
    COMBINE(AL0,AL1,AL2,AH0,AH1,AH2, BL0,BL1,BL2,BH0,BH1,BH2);
    RNORM(AL0,AL1,AL2,AH0,AH1,AH2, S2);

#pragma unroll
    for (int off=1; off<64; off<<=1){
        f32x2 bL0, bL1, bL2; float bH0, bH1, bH2, bS2;
        bL0.x=__shfl_down(AL0.x,(unsigned)off,64); bL0.y=__shfl_down(AL0.y,(unsigned)off,64);
        bL1.x=__shfl_down(AL1.x,(unsigned)off,64); bL1.y=__shfl_down(AL1.y,(unsigned)off,64);
        bL2.x=__shfl_down(AL2.x,(unsigned)off,64); bL2.y=__shfl_down(AL2.y,(unsigned)off,64);
        bH0=__shfl_down(AH0,(unsigned)off,64); bH1=__shfl_down(AH1,(unsigned)off,64);
        bH2=__shfl_down(AH2,(unsigned)off,64); bS2=__shfl_down(S2,(unsigned)off,64);
        COMBINE(AL0,AL1,AL2,AH0,AH1,AH2, bL0,bL1,bL2,bH0,bH1,bH2);
        S2 += bS2;
        RNORM(AL0,AL1,AL2,AH0,AH1,AH2, S2);
    }
#pragma unroll
    for (int off=32; off; off>>=1) sc += __shfl_down(sc, (unsigned)off, 64);

    if (ln == 0){
        float4* r = (float4*)(ws + (size_t)g*16);
        // row-major: V[0][j]=ALj.x, V[1][j]=ALj.y, V[2][j]=AHj
        r[0] = make_float4(AL0.x, AL1.x, AL2.x, AL0.y);
        r[1] = make_float4(AL1.y, AL2.y, AH0,   AH1);
        r[2] = make_float4(AH2,   S2,    sc,    ew[0]);
        r[3] = make_float4(ew[1], ew[2], 0.f,   0.f);
    }
}

// stage 1: one thread per sequence chains 8 records; alpha0 + end fold; partial sums
extern "C" __global__ __launch_bounds__(64)
void crf_fin1(const float* __restrict__ ws, const float* __restrict__ stt,
              const float* __restrict__ ent, float* __restrict__ partial)
{
    const int q = blockIdx.x*64 + threadIdx.x;   // sequence id
    const float* rr = ws + (size_t)q*NCH*16;
    float C[9], S = rr[9], sc = rr[10];
#pragma unroll
    for (int k=0;k<9;++k) C[k]=rr[k];
#pragma unroll
    for (int p=1;p<NCH;++p){
        const float* r = rr + p*16;
        float T[9]; mul33(T, C, r);
        S += r[9]; sc += r[10];
        renorm9(T, S);
#pragma unroll
        for (int k=0;k<9;++k) C[k]=T[k];
    }
    float a0=(stt[0]+rr[11])*LOG2E, a1=(stt[1]+rr[12])*LOG2E, a2=(stt[2]+rr[13])*LOG2E;
    float am = fmaxf(fmaxf(a0,a1),a2);
    float w0=exp2f_(a0-am), w1=exp2f_(a1-am), w2=exp2f_(a2-am);
    float q0=w0*C[0]+w1*C[3]+w2*C[6];
    float q1=w0*C[1]+w1*C[4]+w2*C[7];
    float q2=w0*C[2]+w1*C[5]+w2*C[8];
    float z = q0*exp2f_(ent[0]*LOG2E) + q1*exp2f_(ent[1]*LOG2E) + q2*exp2f_(ent[2]*LOG2E);
    float logz = (am + S + log2f_(z)) * LN2;
    float nll = logz - sc;
#pragma unroll
    for (int off=32; off; off>>=1) nll += __shfl_down(nll, (unsigned)off, 64);
    if (threadIdx.x==0) partial[blockIdx.x] = nll;
}

extern "C" __global__ __launch_bounds__(64)
void crf_fin2(const float* __restrict__ partial, float* __restrict__ out)
{
    float v = (threadIdx.x < 16) ? partial[threadIdx.x] : 0.f;
#pragma unroll
    for (int off=32; off; off>>=1) v += __shfl_down(v, (unsigned)off, 64);
    if (threadIdx.x==0) out[0] = v;
}

extern "C" void kernel_launch(void* const* d_in, const int* in_sizes, int n_in,
                              void* d_out, int out_size, void* d_ws, size_t ws_size,
                              hipStream_t stream) {
    const float* em  = (const float*)d_in[0];
    const int*   lab = (const int*)d_in[1];
    const float* stt = (const float*)d_in[2];
    const float* trt = (const float*)d_in[3];
    const float* ent = (const float*)d_in[4];
    float* out = (float*)d_out;
    float* ws  = (float*)d_ws;                 // 8*B*16 floats = 512 KB records
    const int B = in_sizes[1] / S_;            // 1024
    float* partial = ws + (size_t)NCH*B*16;

    crf_fwd<<<B*NCH/NWAVE, 256, 0, stream>>>(em, lab, stt, trt, ent, ws);
    crf_fin1<<<B/64, 64, 0, stream>>>(ws, stt, ent, partial);
    crf_fin2<<<1, 64, 0, stream>>>(partial, out);
}